// Round 13
// baseline (315.964 us; speedup 1.0000x reference)
//
#include <hip/hip_runtime.h>
#include <hip/hip_bf16.h>
#include <stdint.h>

typedef unsigned short u16;
typedef __attribute__((ext_vector_type(4))) float f32x4;
typedef __attribute__((ext_vector_type(8))) __bf16 bf16x8;
typedef __attribute__((ext_vector_type(8))) unsigned short u16x8;
typedef __attribute__((ext_vector_type(4))) unsigned short u16x4;

#define SEQ 2048
#define HID 2048
#define HD  128

__device__ __forceinline__ float b2f(u16 v) {
    union { float f; unsigned u; } c; c.u = ((unsigned)v) << 16; return c.f;
}
__device__ __forceinline__ u16 f2b(float f) {
    union { float f; unsigned u; } c; c.f = f;
    unsigned r = c.u + 0x7fffu + ((c.u >> 16) & 1u);
    return (u16)(r >> 16);
}
__device__ __forceinline__ bf16x8 tob(u16x8 v) {
    union { u16x8 u; bf16x8 b; } c; c.u = v; return c.b;
}
__device__ __forceinline__ u16x8 ld8(const u16* p) { return *(const u16x8*)p; }

typedef const __attribute__((address_space(1))) unsigned int* gas_ptr;
typedef __attribute__((address_space(3))) unsigned int* las_ptr;
__device__ __forceinline__ void gld16(const void* g, void* l) {
    __builtin_amdgcn_global_load_lds((gas_ptr)g, (las_ptr)l, 16, 0, 0);
}

// ---------------- fused prep: RMSNorm (blocks 0..2047) + qkv-weight conv ----------------
__global__ __launch_bounds__(256) void k_prep(const float* __restrict__ x,
                                              const float* __restrict__ w,
                                              u16* __restrict__ normed,
                                              const float* __restrict__ qkvw,
                                              u16* __restrict__ qkvwb) {
    const int b = blockIdx.x, t = threadIdx.x;
    if (b < 2048) {
        const int row = b;
        const float* xr = x + (size_t)row * HID + t * 8;
        f32x4 xa = *(const f32x4*)xr;
        f32x4 xb = *(const f32x4*)(xr + 4);
        float xf[8]; float ss = 0.f;
#pragma unroll
        for (int e = 0; e < 4; ++e) { xf[e] = xa[e]; xf[e + 4] = xb[e]; }
#pragma unroll
        for (int e = 0; e < 8; ++e) ss += xf[e] * xf[e];
#pragma unroll
        for (int m = 32; m; m >>= 1) ss += __shfl_xor(ss, m);
        __shared__ float red[4];
        if ((t & 63) == 0) red[t >> 6] = ss;
        __syncthreads();
        ss = red[0] + red[1] + red[2] + red[3];
        const float sc = rsqrtf(ss * (1.0f / HID) + 1e-6f);
        f32x4 wa = *(const f32x4*)(w + t * 8);
        f32x4 wb = *(const f32x4*)(w + t * 8 + 4);
        u16x8 ov;
#pragma unroll
        for (int e = 0; e < 4; ++e) {
            ov[e] = f2b(xf[e] * sc * wa[e]);
            ov[e + 4] = f2b(xf[e + 4] * sc * wb[e]);
        }
        *(u16x8*)(normed + (size_t)row * HID + t * 8) = ov;
    } else {
        const size_t i = ((size_t)(b - 2048) * 256 + t) * 8;
        f32x4 a = *(const f32x4*)(qkvw + i);
        f32x4 bb = *(const f32x4*)(qkvw + i + 4);
        u16x8 o;
#pragma unroll
        for (int e = 0; e < 4; ++e) { o[e] = f2b(a[e]); o[e + 4] = f2b(bb[e]); }
        *(u16x8*)(qkvwb + i) = o;
    }
}

// Staging: 8 gld16 per wave per tile. LDS dest linear (rule #21); chunk
// permutation pre-applied to GLOBAL source; reads apply the same XOR.
#define STAGE_G(buf, k0)                                                      \
    do {                                                                      \
        char* a0 = (char*)&As[buf][0][0] + wave * 1024;                       \
        char* a1 = (char*)&As[buf][1][0] + wave * 1024;                       \
        char* b0 = (char*)&Bs[buf][0][0] + wave * 1024;                       \
        char* b1 = (char*)&Bs[buf][1][0] + wave * 1024;                       \
        gld16(ga + (k0), a0);                                                 \
        gld16(ga + (k0) + rowskip, a0 + 4096);                                \
        gld16(ga + (k0) + 32, a1);                                            \
        gld16(ga + (k0) + 32 + rowskip, a1 + 4096);                           \
        gld16(gb + (k0), b0);                                                 \
        gld16(gb + (k0) + rowskip, b0 + 4096);                                \
        gld16(gb + (k0) + 32, b1);                                            \
        gld16(gb + (k0) + 32 + rowskip, b1 + 4096);                           \
    } while (0)

// R5-proven K-loop: dbuf LDS, counted vmcnt(8), swizzled reads. nk = trip count.
#define GEMM_PIPE(nk)                                                         \
    STAGE_G(0, 0);                                                            \
    for (int t = 0; t < (nk); ++t) {                                          \
        const int cur = t & 1;                                                \
        if (t + 1 < (nk)) {                                                   \
            STAGE_G(cur ^ 1, (t + 1) * 64);                                   \
            asm volatile("s_waitcnt vmcnt(8)" ::: "memory");                  \
        } else {                                                              \
            asm volatile("s_waitcnt vmcnt(0)" ::: "memory");                  \
        }                                                                     \
        __builtin_amdgcn_s_barrier();                                         \
        asm volatile("" ::: "memory");                                       \
        _Pragma("unroll")                                                     \
        for (int h = 0; h < 2; ++h) {                                         \
            const u16* as = &As[cur][h][0];                                   \
            const u16* bs = &Bs[cur][h][0];                                   \
            bf16x8 af[4], bfr[4];                                             \
            _Pragma("unroll")                                                 \
            for (int i = 0; i < 4; ++i)                                       \
                af[i] = tob(ld8(as + (wm * 64 + i * 16 + l16) * 32 + ((quad ^ sw) << 3))); \
            _Pragma("unroll")                                                 \
            for (int j = 0; j < 4; ++j)                                       \
                bfr[j] = tob(ld8(bs + (wn * 64 + j * 16 + l16) * 32 + ((quad ^ sw) << 3))); \
            _Pragma("unroll")                                                 \
            for (int i = 0; i < 4; ++i)                                       \
                _Pragma("unroll")                                             \
                for (int j = 0; j < 4; ++j)                                   \
                    acc[i][j] = __builtin_amdgcn_mfma_f32_16x16x32_bf16(af[i], bfr[j], acc[i][j], 0, 0, 0); \
        }                                                                     \
        asm volatile("" ::: "memory");                                       \
        __builtin_amdgcn_s_barrier();                                        \
    }

// ------- QKV GEMM: R5 structure, scatter epilogue -------
__global__ __launch_bounds__(256) void k_gemm_qkv(const u16* __restrict__ A,
                                                  const u16* __restrict__ B,
                                                  u16* __restrict__ qraw,
                                                  u16* __restrict__ kraw,
                                                  u16* __restrict__ vtr,
                                                  int K) {
    __shared__ u16 As[2][2][128 * 32];
    __shared__ u16 Bs[2][2][128 * 32];
    const int tid = threadIdx.x;
    const int wave = tid >> 6, lane = tid & 63, quad = lane >> 4, l16 = lane & 15;
    const int wm = wave >> 1, wn = wave & 1;
    const int sw = (l16 >> 1) & 3;
    const int m0 = blockIdx.x * 128, n0 = blockIdx.y * 128;
    f32x4 acc[4][4];
#pragma unroll
    for (int i = 0; i < 4; ++i)
#pragma unroll
        for (int j = 0; j < 4; ++j) acc[i][j] = (f32x4){0.f, 0.f, 0.f, 0.f};

    const int gchunk = (tid & 3) ^ ((tid >> 3) & 3);
    const u16* ga = A + (size_t)(m0 + (tid >> 2)) * K + gchunk * 8;
    const u16* gb = B + (size_t)(n0 + (tid >> 2)) * K + gchunk * 8;
    const size_t rowskip = (size_t)64 * K;

    GEMM_PIPE(K >> 6)

#pragma unroll
    for (int i = 0; i < 4; ++i) {
        const int row = m0 + wm * 64 + i * 16 + quad * 4;
#pragma unroll
        for (int j = 0; j < 4; ++j) {
            const int col = n0 + wn * 64 + j * 16 + l16;
#pragma unroll
            for (int r = 0; r < 4; ++r) {
                const u16 val = f2b(acc[i][j][r]);
                const int s = row + r;
                if (col < 2048) {
                    const int head = col >> 7, d = col & 127;
                    qraw[((size_t)head * SEQ + s) * HD + d] = val;
                } else if (col < 3072) {
                    const int c = col - 2048, kv = c >> 7, d = c & 127;
                    kraw[((size_t)kv * SEQ + s) * HD + d] = val;
                } else {
                    const int c = col - 3072, kv = c >> 7, d = c & 127;
                    vtr[(size_t)kv * HD * SEQ + (size_t)d * SEQ + s] = val;
                }
            }
        }
    }
}

// ------- O-projection GEMM: BN=64 tiles -> 512 blocks (2/CU overlap, no merge),
//         R5 pipeline with 6 staging loads/thread and counted vmcnt(6), f32 out. -------
__global__ __launch_bounds__(256) void k_gemm_of(const u16* __restrict__ A,
                                                 const u16* __restrict__ B,
                                                 float* __restrict__ C,
                                                 int N, int K) {
    __shared__ u16 As[2][2][128 * 32];
    __shared__ u16 Bs[2][2][64 * 32];
    const int tid = threadIdx.x;
    const int wave = tid >> 6, lane = tid & 63, quad = lane >> 4, l16 = lane & 15;
    const int wm = wave >> 1, wn = wave & 1;
    const int sw = (l16 >> 1) & 3;
    const int m0 = blockIdx.x * 128, n0 = blockIdx.y * 64;
    f32x4 acc[4][2];
#pragma unroll
    for (int i = 0; i < 4; ++i)
#pragma unroll
        for (int j = 0; j < 2; ++j) acc[i][j] = (f32x4){0.f, 0.f, 0.f, 0.f};

    const int gchunk = (tid & 3) ^ ((tid >> 3) & 3);
    const u16* ga = A + (size_t)(m0 + (tid >> 2)) * K + gchunk * 8;
    const u16* gb = B + (size_t)(n0 + (tid >> 2)) * K + gchunk * 8;
    const size_t rowskip = (size_t)64 * K;

#define STAGE_OF(buf, k0)                                                     \
    do {                                                                      \
        char* a0 = (char*)&As[buf][0][0] + wave * 1024;                       \
        char* a1 = (char*)&As[buf][1][0] + wave * 1024;                       \
        char* b0 = (char*)&Bs[buf][0][0] + wave * 1024;                       \
        char* b1 = (char*)&Bs[buf][1][0] + wave * 1024;                       \
        gld16(ga + (k0), a0);                                                 \
        gld16(ga + (k0) + rowskip, a0 + 4096);                                \
        gld16(ga + (k0) + 32, a1);                                            \
        gld16(ga + (k0) + 32 + rowskip, a1 + 4096);                           \
        gld16(gb + (k0), b0);                                                 \
        gld16(gb + (k0) + 32, b1);                                            \
    } while (0)

    STAGE_OF(0, 0);
    const int nk = K >> 6;
    for (int t = 0; t < nk; ++t) {
        const int cur = t & 1;
        if (t + 1 < nk) {
            STAGE_OF(cur ^ 1, (t + 1) * 64);
            asm volatile("s_waitcnt vmcnt(6)" ::: "memory");
        } else {
            asm volatile("s_waitcnt vmcnt(0)" ::: "memory");
        }
        __builtin_amdgcn_s_barrier();
        asm volatile("" ::: "memory");
#pragma unroll
        for (int h = 0; h < 2; ++h) {
            const u16* as = &As[cur][h][0];
            const u16* bs = &Bs[cur][h][0];
            bf16x8 af[4], bfr[2];
#pragma unroll
            for (int i = 0; i < 4; ++i)
                af[i] = tob(ld8(as + (wm * 64 + i * 16 + l16) * 32 + ((quad ^ sw) << 3)));
#pragma unroll
            for (int j = 0; j < 2; ++j)
                bfr[j] = tob(ld8(bs + (wn * 32 + j * 16 + l16) * 32 + ((quad ^ sw) << 3)));
#pragma unroll
            for (int i = 0; i < 4; ++i)
#pragma unroll
                for (int j = 0; j < 2; ++j)
                    acc[i][j] = __builtin_amdgcn_mfma_f32_16x16x32_bf16(af[i], bfr[j], acc[i][j], 0, 0, 0);
        }
        asm volatile("" ::: "memory");
        __builtin_amdgcn_s_barrier();
    }
#undef STAGE_OF

#pragma unroll
    for (int i = 0; i < 4; ++i) {
        const int row = m0 + wm * 64 + i * 16 + quad * 4;
#pragma unroll
        for (int j = 0; j < 2; ++j) {
            const int col = n0 + wn * 32 + j * 16 + l16;
#pragma unroll
            for (int r = 0; r < 4; ++r)
                C[(size_t)(row + r) * N + col] = acc[i][j][r];
        }
    }
}

// ---------------- fused: in-place RoPE + per-head RMSNorm (y<6) + ow conv (y==6) ----------------
__global__ __launch_bounds__(256) void k_ropeconv(const int* __restrict__ pos,
                                                  const float* __restrict__ qw,
                                                  const float* __restrict__ kw,
                                                  u16* __restrict__ qraw,
                                                  u16* __restrict__ kraw,
                                                  const float* __restrict__ ow,
                                                  u16* __restrict__ owb) {
    if (blockIdx.y < 6) {
        const int s = blockIdx.x;
        const int h = blockIdx.y * 4 + (threadIdx.x >> 6);
        const int d = threadIdx.x & 63;
        const bool isq = h < 16;
        u16* row = isq ? (qraw + ((size_t)h * SEQ + s) * HD)
                       : (kraw + ((size_t)(h - 16) * SEQ + s) * HD);
        const float x1 = b2f(row[d]), x2 = b2f(row[d + 64]);
        const float p = (float)pos[s];
        const float inv = exp2f(-(float)d * (2.0f / 128.0f) * 13.287712379549449f);
        const float fr = p * inv;
        const float c = cosf(fr), sn = sinf(fr);
        const float o1 = x1 * c - x2 * sn;
        const float o2 = x2 * c + x1 * sn;
        float ss = o1 * o1 + o2 * o2;
#pragma unroll
        for (int m = 32; m; m >>= 1) ss += __shfl_xor(ss, m);
        const float sc = rsqrtf(ss * (1.0f / HD) + 1e-6f);
        const float* w = isq ? qw : kw;
        row[d] = f2b(o1 * sc * w[d]);
        row[d + 64] = f2b(o2 * sc * w[d + 64]);
    } else {
        const size_t i = ((size_t)blockIdx.x * 256 + threadIdx.x) * 8;
        f32x4 a = *(const f32x4*)(ow + i);
        f32x4 b = *(const f32x4*)(ow + i + 4);
        u16x8 o;
#pragma unroll
        for (int e = 0; e < 4; ++e) { o[e] = f2b(a[e]); o[e + 4] = f2b(b[e]); }
        *(u16x8*)(owb + i) = o;
    }
}

// ---------------- causal flash attention: slot-permuted P + L=8 split-K ----------------
// K-tile rows staged at LDS row rho(kp) = (kp&35)|((kp&4)<<2)|((kp&24)>>1). Then
// QK^T slot (j,quad,r) holds P at physical kpos 32(j>>1)+8*quad+4(j&1)+r, which IS
// A-fragment element (kk=j>>1, e=4(j&1)+r) for PV -> ap built in-lane from accs
// (no P LDS round-trip). Sum over k is permutation-invariant; V stays identity.
// LDS = 32 KB exactly -> 5 blocks/CU; split np=ceil((qt+1)/8) -> max 8 serial
// iters, 80 blocks/head = 1280 = 5*256 all resident. Partials for s>=512 merged
// by k_amerge (po compacted to rows 512..2047).
__global__ __launch_bounds__(256, 5) void k_attn(const u16* __restrict__ qh,
                                                 const u16* __restrict__ kh,
                                                 const u16* __restrict__ vt,
                                                 u16* __restrict__ out,
                                                 u16* __restrict__ po,
                                                 float* __restrict__ pl) {
    const int tid = threadIdx.x;
    const int wave = tid >> 6, lane = tid & 63, quad = lane >> 4, l16 = lane & 15;
    const int head = blockIdx.y;
    const int b = blockIdx.x;            // 0..79
    int qt, part, np;
    if (b < 8)       { qt = b;                    part = 0;            np = 1; }
    else if (b < 24) { qt = 8 + ((b - 8) >> 1);   part = (b - 8) & 1;  np = 2; }
    else if (b < 48) { qt = 16 + (b - 24) / 3;    part = (b - 24) % 3; np = 3; }
    else             { qt = 24 + ((b - 48) >> 2); part = (b - 48) & 3; np = 4; }
    const int kvh = head >> 1;
    const int q0 = qt * 64;
    const int ntiles = qt + 1;

    __shared__ u16 Ks[64 * 128];
    __shared__ u16 Vts[128 * 64];

    const u16* qbase = qh + ((size_t)head * SEQ + q0 + wave * 16) * HD;
    bf16x8 aq[4];
#pragma unroll
    for (int kk = 0; kk < 4; ++kk)
        aq[kk] = tob(ld8(qbase + l16 * HD + kk * 32 + quad * 8));

    f32x4 acco[8];
#pragma unroll
    for (int j = 0; j < 8; ++j) acco[j] = (f32x4){0.f, 0.f, 0.f, 0.f};
    float lsum = 0.f;

    const float sc = 0.08838834764831845f; // 1/sqrt(128)
    const u16* kbase = kh + (size_t)kvh * SEQ * HD;
    const u16* vbase = vt + (size_t)kvh * HD * SEQ;
    const int qrow_g = q0 + wave * 16 + l16;

    const u16* kg0 = kbase + (size_t)tid * 8;
    const u16* vg0 = vbase + (size_t)(tid >> 3) * SEQ + (size_t)(tid & 7) * 8;
    int kst[4], vst[4];
#pragma unroll
    for (int r = 0; r < 4; ++r) {
        const int kp = r * 16 + (tid >> 4);                       // physical tile row loaded
        const int u = (kp & 35) | ((kp & 4) << 2) | ((kp & 24) >> 1); // rho(kp)
        kst[r] = u * 128 + (((tid & 15) ^ (u & 7)) << 3);
        const int vrow = r * 32 + (tid >> 3);
        vst[r] = vrow * 64 + (((tid & 7) ^ (vrow & 7)) << 3);
    }

    // prologue: stage tile kt=part (always < ntiles)
    u16x8 kreg[4], vreg[4];
    {
        const size_t koff = (size_t)part * 64;
#pragma unroll
        for (int r = 0; r < 4; ++r) {
            kreg[r] = ld8(kg0 + koff * HD + (size_t)r * 2048);
            vreg[r] = ld8(vg0 + koff + (size_t)r * 32 * SEQ);
        }
#pragma unroll
        for (int r = 0; r < 4; ++r) {
            *(u16x8*)(&Ks[0] + kst[r]) = kreg[r];
            *(u16x8*)(&Vts[0] + vst[r]) = vreg[r];
        }
    }
    __syncthreads();

    for (int kt = part; kt < ntiles; kt += np) {
        const bool havenext = (kt + np) < ntiles;
        if (havenext) {
            const size_t koff = (size_t)(kt + np) * 64;
#pragma unroll
            for (int r = 0; r < 4; ++r) {
                kreg[r] = ld8(kg0 + koff * HD + (size_t)r * 2048);
                vreg[r] = ld8(vg0 + koff + (size_t)r * 32 * SEQ);
            }
        }

        // S^T = K Q^T (K rows permuted by rho in LDS)
        f32x4 accs[4];
#pragma unroll
        for (int j = 0; j < 4; ++j) accs[j] = (f32x4){0.f, 0.f, 0.f, 0.f};
#pragma unroll
        for (int kk = 0; kk < 4; ++kk) {
#pragma unroll
            for (int j = 0; j < 4; ++j) {
                const int krow = j * 16 + l16;
                const bf16x8 bk = tob(ld8(&Ks[0] + krow * 128 + (((kk * 4 + quad) ^ (krow & 7)) << 3)));
                accs[j] = __builtin_amdgcn_mfma_f32_16x16x32_bf16(bk, aq[kk], accs[j], 0, 0, 0);
            }
        }

        // P = exp(s*sc) (M=0), causal mask; pack A-fragments IN-LANE (slot permutation)
        const int k0 = kt * 64;
        u16x8 apk[2];
#pragma unroll
        for (int j = 0; j < 4; ++j) {
#pragma unroll
            for (int r = 0; r < 4; ++r) {
                const int kpos = k0 + ((j >> 1) << 5) + (quad << 3) + ((j & 1) << 2) + r;
                const float pv = (kpos > qrow_g) ? 0.f : __expf(accs[j][r] * sc);
                lsum += pv;
                apk[j >> 1][((j & 1) << 2) + r] = f2b(pv);
            }
        }

        // O += P V (ap lane-local; V identity layout)
#pragma unroll
        for (int kk = 0; kk < 2; ++kk) {
            const bf16x8 ap = tob(apk[kk]);
#pragma unroll
            for (int j = 0; j < 8; ++j) {
                const int vrow = j * 16 + l16;
                const bf16x8 bv = tob(ld8(&Vts[0] + vrow * 64 + (((kk * 4 + quad) ^ (vrow & 7)) << 3)));
                acco[j] = __builtin_amdgcn_mfma_f32_16x16x32_bf16(ap, bv, acco[j], 0, 0, 0);
            }
        }

        __syncthreads(); // all reads of this tile done
        if (havenext) {
#pragma unroll
            for (int r = 0; r < 4; ++r) {
                *(u16x8*)(&Ks[0] + kst[r]) = kreg[r];
                *(u16x8*)(&Vts[0] + vst[r]) = vreg[r];
            }
        }
        __syncthreads(); // stores visible before next-iter reads
    }

    // per-row l reduction (lanes sharing l16 hold partials across kpos)
    float v = lsum;
    v += __shfl_xor(v, 16);
    v += __shfl_xor(v, 32);
    const int rowb = q0 + wave * 16 + quad * 4;

    if (np == 1) {
        f32x4 il;
#pragma unroll
        for (int r = 0; r < 4; ++r) il[r] = 1.0f / __shfl(v, quad * 4 + r);
#pragma unroll
        for (int j = 0; j < 8; ++j) {
            const int col = head * HD + j * 16 + l16;
#pragma unroll
            for (int r = 0; r < 4; ++r)
                out[(size_t)(rowb + r) * 2048 + col] = f2b(acco[j][r] * il[r]);
        }
    } else {
        u16* pob = po + (size_t)part * (1536 * 2048);
        float* plb = pl + (size_t)part * (16 * 1536) + (size_t)head * 1536;
        if (lane < 16) plb[q0 + wave * 16 + l16 - 512] = v;
#pragma unroll
        for (int j = 0; j < 8; ++j) {
            const int col = head * HD + j * 16 + l16;
#pragma unroll
            for (int r = 0; r < 4; ++r)
                pob[(size_t)(rowb + r - 512) * 2048 + col] = f2b(acco[j][r]);
        }
    }
}

// ---------------- split-K merge + normalize for rows s >= 512 ----------------
__global__ __launch_bounds__(256) void k_amerge(const u16* __restrict__ po,
                                                const float* __restrict__ pl,
                                                u16* __restrict__ out) {
    const int s = blockIdx.x + 512;
    const int qt = s >> 6;
    const int np = (qt >= 24) ? 4 : (qt >= 16) ? 3 : 2;
    const int t = threadIdx.x;
    const int head = t >> 4;

    float l = 0.f;
#pragma unroll
    for (int p = 0; p < 4; ++p)
        if (p < np) l += pl[(size_t)p * (16 * 1536) + (size_t)head * 1536 + (s - 512)];
    const float il = 1.0f / l;

    float o[8] = {0.f, 0.f, 0.f, 0.f, 0.f, 0.f, 0.f, 0.f};
#pragma unroll
    for (int p = 0; p < 4; ++p) {
        if (p < np) {
            const u16x8 vv = ld8(po + (size_t)p * (1536 * 2048) + (size_t)(s - 512) * 2048 + t * 8);
#pragma unroll
            for (int e = 0; e < 8; ++e) o[e] += b2f(vv[e]);
        }
    }
    u16x8 ov;
#pragma unroll
    for (int e = 0; e < 8; ++e) ov[e] = f2b(o[e] * il);
    *(u16x8*)(out + (size_t)s * 2048 + t * 8) = ov;
}

extern "C" void kernel_launch(void* const* d_in, const int* in_sizes, int n_in,
                              void* d_out, int out_size, void* d_ws, size_t ws_size,
                              hipStream_t stream) {
    const int*   positions = (const int*)d_in[0];
    const float* hidden   = (const float*)d_in[1];
    const float* lnw      = (const float*)d_in[2];
    const float* qkvw     = (const float*)d_in[3];
    const float* qnw      = (const float*)d_in[4];
    const float* knw      = (const float*)d_in[5];
    const float* ow       = (const float*)d_in[6];
    float* outp = (float*)d_out;

    char* ws = (char*)d_ws;
    const size_t MB = 1024ull * 1024ull;
    u16* normed = (u16*)(ws + 0 * MB);   // [S][2048] bf16 — dead after QKV gemm
    u16* qraw   = (u16*)(ws + 8 * MB);   // [16][S][128] — dead after attn
    u16* kraw   = (u16*)(ws + 16 * MB);  // [8][S][128]  — dead after attn
    u16* vtr    = (u16*)(ws + 20 * MB);  // [8][128][S]  — dead after attn
    u16* qkvwb  = (u16*)(ws + 24 * MB);  // [4096][2048] bf16 — dead after QKV gemm
    u16* owb    = (u16*)(ws + 0 * MB);   // [2048][2048] bf16, overwrites normed (after qkv)
    u16* attno  = (u16*)(ws + 24 * MB);  // [S][2048] bf16, overwrites qkvwb head
    u16* po     = (u16*)(ws + 32 * MB);  // [4][1536][2048] bf16 attn partials (24MB)
    float* pl   = (float*)(ws + 56 * MB);// [4][16][1536] f32 attn l-partials (384KB)

    k_prep    <<<6144, 256, 0, stream>>>(hidden, lnw, normed, qkvw, qkvwb);
    k_gemm_qkv<<<dim3(16, 32), 256, 0, stream>>>(normed, qkvwb, qraw, kraw, vtr, HID);
    k_ropeconv<<<dim3(SEQ, 7), 256, 0, stream>>>(positions, qnw, knw, qraw, kraw, ow, owb);
    k_attn    <<<dim3(80, 16), 256, 0, stream>>>(qraw, kraw, vtr, attno, po, pl);
    k_amerge  <<<1536, 256, 0, stream>>>(po, pl, attno);
    k_gemm_of <<<dim3(16, 32), 256, 0, stream>>>(attno, owb, outp, HID, HID);
}

// Round 14
// 244.578 us; speedup vs baseline: 1.2919x; 1.2919x over previous
//
#include <hip/hip_runtime.h>
#include <hip/hip_bf16.h>
#include <stdint.h>

typedef unsigned short u16;
typedef __attribute__((ext_vector_type(4))) float f32x4;
typedef __attribute__((ext_vector_type(8))) __bf16 bf16x8;
typedef __attribute__((ext_vector_type(8))) unsigned short u16x8;
typedef __attribute__((ext_vector_type(4))) unsigned short u16x4;

#define SEQ 2048
#define HID 2048
#define HD  128

__device__ __forceinline__ float b2f(u16 v) {
    union { float f; unsigned u; } c; c.u = ((unsigned)v) << 16; return c.f;
}
__device__ __forceinline__ u16 f2b(float f) {
    union { float f; unsigned u; } c; c.f = f;
    unsigned r = c.u + 0x7fffu + ((c.u >> 16) & 1u);
    return (u16)(r >> 16);
}
__device__ __forceinline__ bf16x8 tob(u16x8 v) {
    union { u16x8 u; bf16x8 b; } c; c.u = v; return c.b;
}
__device__ __forceinline__ u16x8 ld8(const u16* p) { return *(const u16x8*)p; }

typedef const __attribute__((address_space(1))) unsigned int* gas_ptr;
typedef __attribute__((address_space(3))) unsigned int* las_ptr;
__device__ __forceinline__ void gld16(const void* g, void* l) {
    __builtin_amdgcn_global_load_lds((gas_ptr)g, (las_ptr)l, 16, 0, 0);
}

// ---------------- fused prep: RMSNorm (blocks 0..2047) + qkv-weight conv ----------------
__global__ __launch_bounds__(256) void k_prep(const float* __restrict__ x,
                                              const float* __restrict__ w,
                                              u16* __restrict__ normed,
                                              const float* __restrict__ qkvw,
                                              u16* __restrict__ qkvwb) {
    const int b = blockIdx.x, t = threadIdx.x;
    if (b < 2048) {
        const int row = b;
        const float* xr = x + (size_t)row * HID + t * 8;
        f32x4 xa = *(const f32x4*)xr;
        f32x4 xb = *(const f32x4*)(xr + 4);
        float xf[8]; float ss = 0.f;
#pragma unroll
        for (int e = 0; e < 4; ++e) { xf[e] = xa[e]; xf[e + 4] = xb[e]; }
#pragma unroll
        for (int e = 0; e < 8; ++e) ss += xf[e] * xf[e];
#pragma unroll
        for (int m = 32; m; m >>= 1) ss += __shfl_xor(ss, m);
        __shared__ float red[4];
        if ((t & 63) == 0) red[t >> 6] = ss;
        __syncthreads();
        ss = red[0] + red[1] + red[2] + red[3];
        const float sc = rsqrtf(ss * (1.0f / HID) + 1e-6f);
        f32x4 wa = *(const f32x4*)(w + t * 8);
        f32x4 wb = *(const f32x4*)(w + t * 8 + 4);
        u16x8 ov;
#pragma unroll
        for (int e = 0; e < 4; ++e) {
            ov[e] = f2b(xf[e] * sc * wa[e]);
            ov[e + 4] = f2b(xf[e + 4] * sc * wb[e]);
        }
        *(u16x8*)(normed + (size_t)row * HID + t * 8) = ov;
    } else {
        const size_t i = ((size_t)(b - 2048) * 256 + t) * 8;
        f32x4 a = *(const f32x4*)(qkvw + i);
        f32x4 bb = *(const f32x4*)(qkvw + i + 4);
        u16x8 o;
#pragma unroll
        for (int e = 0; e < 4; ++e) { o[e] = f2b(a[e]); o[e + 4] = f2b(bb[e]); }
        *(u16x8*)(qkvwb + i) = o;
    }
}

// Staging: 8 gld16 per wave per tile. LDS dest linear (rule #21); chunk
// permutation pre-applied to GLOBAL source; reads apply the same XOR.
#define STAGE_G(buf, k0)                                                      \
    do {                                                                      \
        char* a0 = (char*)&As[buf][0][0] + wave * 1024;                       \
        char* a1 = (char*)&As[buf][1][0] + wave * 1024;                       \
        char* b0 = (char*)&Bs[buf][0][0] + wave * 1024;                       \
        char* b1 = (char*)&Bs[buf][1][0] + wave * 1024;                       \
        gld16(ga + (k0), a0);                                                 \
        gld16(ga + (k0) + rowskip, a0 + 4096);                                \
        gld16(ga + (k0) + 32, a1);                                            \
        gld16(ga + (k0) + 32 + rowskip, a1 + 4096);                           \
        gld16(gb + (k0), b0);                                                 \
        gld16(gb + (k0) + rowskip, b0 + 4096);                                \
        gld16(gb + (k0) + 32, b1);                                            \
        gld16(gb + (k0) + 32 + rowskip, b1 + 4096);                           \
    } while (0)

// R5-proven K-loop: dbuf LDS, counted vmcnt(8), swizzled reads. nk = trip count.
#define GEMM_PIPE(nk)                                                         \
    STAGE_G(0, 0);                                                            \
    for (int t = 0; t < (nk); ++t) {                                          \
        const int cur = t & 1;                                                \
        if (t + 1 < (nk)) {                                                   \
            STAGE_G(cur ^ 1, (t + 1) * 64);                                   \
            asm volatile("s_waitcnt vmcnt(8)" ::: "memory");                  \
        } else {                                                              \
            asm volatile("s_waitcnt vmcnt(0)" ::: "memory");                  \
        }                                                                     \
        __builtin_amdgcn_s_barrier();                                         \
        asm volatile("" ::: "memory");                                       \
        _Pragma("unroll")                                                     \
        for (int h = 0; h < 2; ++h) {                                         \
            const u16* as = &As[cur][h][0];                                   \
            const u16* bs = &Bs[cur][h][0];                                   \
            bf16x8 af[4], bfr[4];                                             \
            _Pragma("unroll")                                                 \
            for (int i = 0; i < 4; ++i)                                       \
                af[i] = tob(ld8(as + (wm * 64 + i * 16 + l16) * 32 + ((quad ^ sw) << 3))); \
            _Pragma("unroll")                                                 \
            for (int j = 0; j < 4; ++j)                                       \
                bfr[j] = tob(ld8(bs + (wn * 64 + j * 16 + l16) * 32 + ((quad ^ sw) << 3))); \
            _Pragma("unroll")                                                 \
            for (int i = 0; i < 4; ++i)                                       \
                _Pragma("unroll")                                             \
                for (int j = 0; j < 4; ++j)                                   \
                    acc[i][j] = __builtin_amdgcn_mfma_f32_16x16x32_bf16(af[i], bfr[j], acc[i][j], 0, 0, 0); \
        }                                                                     \
        asm volatile("" ::: "memory");                                       \
        __builtin_amdgcn_s_barrier();                                        \
    }

// ------- QKV GEMM: R5 structure, scatter epilogue -------
__global__ __launch_bounds__(256) void k_gemm_qkv(const u16* __restrict__ A,
                                                  const u16* __restrict__ B,
                                                  u16* __restrict__ qraw,
                                                  u16* __restrict__ kraw,
                                                  u16* __restrict__ vtr,
                                                  int K) {
    __shared__ u16 As[2][2][128 * 32];
    __shared__ u16 Bs[2][2][128 * 32];
    const int tid = threadIdx.x;
    const int wave = tid >> 6, lane = tid & 63, quad = lane >> 4, l16 = lane & 15;
    const int wm = wave >> 1, wn = wave & 1;
    const int sw = (l16 >> 1) & 3;
    const int m0 = blockIdx.x * 128, n0 = blockIdx.y * 128;
    f32x4 acc[4][4];
#pragma unroll
    for (int i = 0; i < 4; ++i)
#pragma unroll
        for (int j = 0; j < 4; ++j) acc[i][j] = (f32x4){0.f, 0.f, 0.f, 0.f};

    const int gchunk = (tid & 3) ^ ((tid >> 3) & 3);
    const u16* ga = A + (size_t)(m0 + (tid >> 2)) * K + gchunk * 8;
    const u16* gb = B + (size_t)(n0 + (tid >> 2)) * K + gchunk * 8;
    const size_t rowskip = (size_t)64 * K;

    GEMM_PIPE(K >> 6)

#pragma unroll
    for (int i = 0; i < 4; ++i) {
        const int row = m0 + wm * 64 + i * 16 + quad * 4;
#pragma unroll
        for (int j = 0; j < 4; ++j) {
            const int col = n0 + wn * 64 + j * 16 + l16;
#pragma unroll
            for (int r = 0; r < 4; ++r) {
                const u16 val = f2b(acc[i][j][r]);
                const int s = row + r;
                if (col < 2048) {
                    const int head = col >> 7, d = col & 127;
                    qraw[((size_t)head * SEQ + s) * HD + d] = val;
                } else if (col < 3072) {
                    const int c = col - 2048, kv = c >> 7, d = c & 127;
                    kraw[((size_t)kv * SEQ + s) * HD + d] = val;
                } else {
                    const int c = col - 3072, kv = c >> 7, d = c & 127;
                    vtr[(size_t)kv * HD * SEQ + (size_t)d * SEQ + s] = val;
                }
            }
        }
    }
}

// ------- O-projection GEMM: BN=64 tiles -> 512 blocks (2/CU overlap, no merge),
//         R5 pipeline with 6 staging loads/thread and counted vmcnt(6), f32 out. -------
__global__ __launch_bounds__(256) void k_gemm_of(const u16* __restrict__ A,
                                                 const u16* __restrict__ B,
                                                 float* __restrict__ C,
                                                 int N, int K) {
    __shared__ u16 As[2][2][128 * 32];
    __shared__ u16 Bs[2][2][64 * 32];
    const int tid = threadIdx.x;
    const int wave = tid >> 6, lane = tid & 63, quad = lane >> 4, l16 = lane & 15;
    const int wm = wave >> 1, wn = wave & 1;
    const int sw = (l16 >> 1) & 3;
    const int m0 = blockIdx.x * 128, n0 = blockIdx.y * 64;
    f32x4 acc[4][2];
#pragma unroll
    for (int i = 0; i < 4; ++i)
#pragma unroll
        for (int j = 0; j < 2; ++j) acc[i][j] = (f32x4){0.f, 0.f, 0.f, 0.f};

    const int gchunk = (tid & 3) ^ ((tid >> 3) & 3);
    const u16* ga = A + (size_t)(m0 + (tid >> 2)) * K + gchunk * 8;
    const u16* gb = B + (size_t)(n0 + (tid >> 2)) * K + gchunk * 8;
    const size_t rowskip = (size_t)64 * K;

#define STAGE_OF(buf, k0)                                                     \
    do {                                                                      \
        char* a0 = (char*)&As[buf][0][0] + wave * 1024;                       \
        char* a1 = (char*)&As[buf][1][0] + wave * 1024;                       \
        char* b0 = (char*)&Bs[buf][0][0] + wave * 1024;                       \
        char* b1 = (char*)&Bs[buf][1][0] + wave * 1024;                       \
        gld16(ga + (k0), a0);                                                 \
        gld16(ga + (k0) + rowskip, a0 + 4096);                                \
        gld16(ga + (k0) + 32, a1);                                            \
        gld16(ga + (k0) + 32 + rowskip, a1 + 4096);                           \
        gld16(gb + (k0), b0);                                                 \
        gld16(gb + (k0) + 32, b1);                                            \
    } while (0)

    STAGE_OF(0, 0);
    const int nk = K >> 6;
    for (int t = 0; t < nk; ++t) {
        const int cur = t & 1;
        if (t + 1 < nk) {
            STAGE_OF(cur ^ 1, (t + 1) * 64);
            asm volatile("s_waitcnt vmcnt(6)" ::: "memory");
        } else {
            asm volatile("s_waitcnt vmcnt(0)" ::: "memory");
        }
        __builtin_amdgcn_s_barrier();
        asm volatile("" ::: "memory");
#pragma unroll
        for (int h = 0; h < 2; ++h) {
            const u16* as = &As[cur][h][0];
            const u16* bs = &Bs[cur][h][0];
            bf16x8 af[4], bfr[2];
#pragma unroll
            for (int i = 0; i < 4; ++i)
                af[i] = tob(ld8(as + (wm * 64 + i * 16 + l16) * 32 + ((quad ^ sw) << 3)));
#pragma unroll
            for (int j = 0; j < 2; ++j)
                bfr[j] = tob(ld8(bs + (wn * 32 + j * 16 + l16) * 32 + ((quad ^ sw) << 3)));
#pragma unroll
            for (int i = 0; i < 4; ++i)
#pragma unroll
                for (int j = 0; j < 2; ++j)
                    acc[i][j] = __builtin_amdgcn_mfma_f32_16x16x32_bf16(af[i], bfr[j], acc[i][j], 0, 0, 0);
        }
        asm volatile("" ::: "memory");
        __builtin_amdgcn_s_barrier();
    }
#undef STAGE_OF

#pragma unroll
    for (int i = 0; i < 4; ++i) {
        const int row = m0 + wm * 64 + i * 16 + quad * 4;
#pragma unroll
        for (int j = 0; j < 2; ++j) {
            const int col = n0 + wn * 32 + j * 16 + l16;
#pragma unroll
            for (int r = 0; r < 4; ++r)
                C[(size_t)(row + r) * N + col] = acc[i][j][r];
        }
    }
}

// ---------------- fused: in-place RoPE + per-head RMSNorm (y<6) + ow conv (y==6) ----------------
__global__ __launch_bounds__(256) void k_ropeconv(const int* __restrict__ pos,
                                                  const float* __restrict__ qw,
                                                  const float* __restrict__ kw,
                                                  u16* __restrict__ qraw,
                                                  u16* __restrict__ kraw,
                                                  const float* __restrict__ ow,
                                                  u16* __restrict__ owb) {
    if (blockIdx.y < 6) {
        const int s = blockIdx.x;
        const int h = blockIdx.y * 4 + (threadIdx.x >> 6);
        const int d = threadIdx.x & 63;
        const bool isq = h < 16;
        u16* row = isq ? (qraw + ((size_t)h * SEQ + s) * HD)
                       : (kraw + ((size_t)(h - 16) * SEQ + s) * HD);
        const float x1 = b2f(row[d]), x2 = b2f(row[d + 64]);
        const float p = (float)pos[s];
        const float inv = exp2f(-(float)d * (2.0f / 128.0f) * 13.287712379549449f);
        const float fr = p * inv;
        const float c = cosf(fr), sn = sinf(fr);
        const float o1 = x1 * c - x2 * sn;
        const float o2 = x2 * c + x1 * sn;
        float ss = o1 * o1 + o2 * o2;
#pragma unroll
        for (int m = 32; m; m >>= 1) ss += __shfl_xor(ss, m);
        const float sc = rsqrtf(ss * (1.0f / HD) + 1e-6f);
        const float* w = isq ? qw : kw;
        row[d] = f2b(o1 * sc * w[d]);
        row[d + 64] = f2b(o2 * sc * w[d + 64]);
    } else {
        const size_t i = ((size_t)blockIdx.x * 256 + threadIdx.x) * 8;
        f32x4 a = *(const f32x4*)(ow + i);
        f32x4 b = *(const f32x4*)(ow + i + 4);
        u16x8 o;
#pragma unroll
        for (int e = 0; e < 4; ++e) { o[e] = f2b(a[e]); o[e + 4] = f2b(b[e]); }
        *(u16x8*)(owb + i) = o;
    }
}

// ---------------- causal flash attention: R12 split (L=11) + slot-permuted P ----------------
// Split-K across blocks (R12-proven): qt<=10 -> 1 block, qt 11..21 -> 2, qt>=22 -> 3;
// max 11 serial iters; partials only rows >= 704 (np<=3) -> L2-friendly traffic.
// NEW (verified on-device in R13): K-tile rows staged at LDS row rho(kp) =
// (kp&35)|((kp&4)<<2)|((kp&24)>>1). QK^T slot (j,quad,r) then holds P at physical
// kpos 32(j>>1)+8*quad+4(j&1)+r == A-fragment element (kk=j>>1, e=4(j&1)+r), so the
// PV A-operand is packed IN-LANE from accs: Ps (8KB LDS) + its ds_write/ds_read
// round-trip are deleted from the serial chain. V layout unchanged (sum over k is
// permutation-invariant). LDS = 32KB; grid 1008 blocks all resident.
__global__ __launch_bounds__(256, 4) void k_attn(const u16* __restrict__ qh,
                                                 const u16* __restrict__ kh,
                                                 const u16* __restrict__ vt,
                                                 u16* __restrict__ out,
                                                 u16* __restrict__ po,
                                                 float* __restrict__ pl) {
    const int tid = threadIdx.x;
    const int wave = tid >> 6, lane = tid & 63, quad = lane >> 4, l16 = lane & 15;
    const int head = blockIdx.y;
    const int b = blockIdx.x;            // 0..62
    int qt, part, np;
    if (b < 11)      { qt = b;                      part = 0;            np = 1; }
    else if (b < 33) { qt = 11 + ((b - 11) >> 1);   part = (b - 11) & 1; np = 2; }
    else             { qt = 22 + (b - 33) / 3;      part = (b - 33) % 3; np = 3; }
    const int kvh = head >> 1;
    const int q0 = qt * 64;
    const int ntiles = qt + 1;

    __shared__ u16 Ks[64 * 128];
    __shared__ u16 Vts[128 * 64];

    const u16* qbase = qh + ((size_t)head * SEQ + q0 + wave * 16) * HD;
    bf16x8 aq[4];
#pragma unroll
    for (int kk = 0; kk < 4; ++kk)
        aq[kk] = tob(ld8(qbase + l16 * HD + kk * 32 + quad * 8));

    f32x4 acco[8];
#pragma unroll
    for (int j = 0; j < 8; ++j) acco[j] = (f32x4){0.f, 0.f, 0.f, 0.f};
    float lsum = 0.f;

    const float sc = 0.08838834764831845f; // 1/sqrt(128)
    const u16* kbase = kh + (size_t)kvh * SEQ * HD;
    const u16* vbase = vt + (size_t)kvh * HD * SEQ;
    const int qrow_g = q0 + wave * 16 + l16;

    const u16* kg0 = kbase + (size_t)tid * 8;
    const u16* vg0 = vbase + (size_t)(tid >> 3) * SEQ + (size_t)(tid & 7) * 8;
    int kst[4], vst[4];
#pragma unroll
    for (int r = 0; r < 4; ++r) {
        const int kp = r * 16 + (tid >> 4);                           // physical tile row
        const int u = (kp & 35) | ((kp & 4) << 2) | ((kp & 24) >> 1); // rho(kp)
        kst[r] = u * 128 + (((tid & 15) ^ (u & 7)) << 3);
        const int vrow = r * 32 + (tid >> 3);
        vst[r] = vrow * 64 + (((tid & 7) ^ (vrow & 7)) << 3);
    }

    // prologue: stage tile kt=part (always < ntiles)
    u16x8 kreg[4], vreg[4];
    {
        const size_t koff = (size_t)part * 64;
#pragma unroll
        for (int r = 0; r < 4; ++r) {
            kreg[r] = ld8(kg0 + koff * HD + (size_t)r * 2048);
            vreg[r] = ld8(vg0 + koff + (size_t)r * 32 * SEQ);
        }
#pragma unroll
        for (int r = 0; r < 4; ++r) {
            *(u16x8*)(&Ks[0] + kst[r]) = kreg[r];
            *(u16x8*)(&Vts[0] + vst[r]) = vreg[r];
        }
    }
    __syncthreads();

    for (int kt = part; kt < ntiles; kt += np) {
        const bool havenext = (kt + np) < ntiles;
        if (havenext) {
            const size_t koff = (size_t)(kt + np) * 64;
#pragma unroll
            for (int r = 0; r < 4; ++r) {
                kreg[r] = ld8(kg0 + koff * HD + (size_t)r * 2048);
                vreg[r] = ld8(vg0 + koff + (size_t)r * 32 * SEQ);
            }
        }

        // S^T = K Q^T (K rows permuted by rho in LDS)
        f32x4 accs[4];
#pragma unroll
        for (int j = 0; j < 4; ++j) accs[j] = (f32x4){0.f, 0.f, 0.f, 0.f};
#pragma unroll
        for (int kk = 0; kk < 4; ++kk) {
#pragma unroll
            for (int j = 0; j < 4; ++j) {
                const int krow = j * 16 + l16;
                const bf16x8 bk = tob(ld8(&Ks[0] + krow * 128 + (((kk * 4 + quad) ^ (krow & 7)) << 3)));
                accs[j] = __builtin_amdgcn_mfma_f32_16x16x32_bf16(bk, aq[kk], accs[j], 0, 0, 0);
            }
        }

        // P = exp(s*sc) (M=0), causal mask; pack PV A-fragments IN-LANE
        const int k0 = kt * 64;
        u16x8 apk[2];
#pragma unroll
        for (int j = 0; j < 4; ++j) {
#pragma unroll
            for (int r = 0; r < 4; ++r) {
                const int kpos = k0 + ((j >> 1) << 5) + (quad << 3) + ((j & 1) << 2) + r;
                const float pv = (kpos > qrow_g) ? 0.f : __expf(accs[j][r] * sc);
                lsum += pv;
                apk[j >> 1][((j & 1) << 2) + r] = f2b(pv);
            }
        }

        // O += P V (ap lane-local; V identity layout)
#pragma unroll
        for (int kk = 0; kk < 2; ++kk) {
            const bf16x8 ap = tob(apk[kk]);
#pragma unroll
            for (int j = 0; j < 8; ++j) {
                const int vrow = j * 16 + l16;
                const bf16x8 bv = tob(ld8(&Vts[0] + vrow * 64 + (((kk * 4 + quad) ^ (vrow & 7)) << 3)));
                acco[j] = __builtin_amdgcn_mfma_f32_16x16x32_bf16(ap, bv, acco[j], 0, 0, 0);
            }
        }

        __syncthreads(); // all reads of this tile done
        if (havenext) {
#pragma unroll
            for (int r = 0; r < 4; ++r) {
                *(u16x8*)(&Ks[0] + kst[r]) = kreg[r];
                *(u16x8*)(&Vts[0] + vst[r]) = vreg[r];
            }
        }
        __syncthreads(); // stores visible before next-iter reads
    }

    // per-row l reduction (lanes sharing l16 hold partials across kpos)
    float v = lsum;
    v += __shfl_xor(v, 16);
    v += __shfl_xor(v, 32);
    const int rowb = q0 + wave * 16 + quad * 4;

    if (np == 1) {
        f32x4 il;
#pragma unroll
        for (int r = 0; r < 4; ++r) il[r] = 1.0f / __shfl(v, quad * 4 + r);
#pragma unroll
        for (int j = 0; j < 8; ++j) {
            const int col = head * HD + j * 16 + l16;
#pragma unroll
            for (int r = 0; r < 4; ++r)
                out[(size_t)(rowb + r) * 2048 + col] = f2b(acco[j][r] * il[r]);
        }
    } else {
        u16* pob = po + (size_t)part * SEQ * 2048;
        float* plb = pl + (size_t)part * 16 * SEQ;
        if (lane < 16) plb[head * SEQ + q0 + wave * 16 + l16] = v;
#pragma unroll
        for (int j = 0; j < 8; ++j) {
            const int col = head * HD + j * 16 + l16;
#pragma unroll
            for (int r = 0; r < 4; ++r)
                pob[(size_t)(rowb + r) * 2048 + col] = f2b(acco[j][r]);
        }
    }
}

// ---------------- split-K merge + normalize for rows s >= 704 ----------------
__global__ __launch_bounds__(256) void k_amerge(const u16* __restrict__ po,
                                                const float* __restrict__ pl,
                                                u16* __restrict__ out) {
    const int s = blockIdx.x + 704;
    const int qt = s >> 6;
    const int np = (qt > 21) ? 3 : 2;
    const int t = threadIdx.x;
    const int head = t >> 4;

    float l = 0.f;
#pragma unroll
    for (int p = 0; p < 3; ++p)
        if (p < np) l += pl[(size_t)p * 16 * SEQ + head * SEQ + s];
    const float il = 1.0f / l;

    float o[8] = {0.f, 0.f, 0.f, 0.f, 0.f, 0.f, 0.f, 0.f};
#pragma unroll
    for (int p = 0; p < 3; ++p) {
        if (p < np) {
            const u16x8 vv = ld8(po + (size_t)p * SEQ * 2048 + (size_t)s * 2048 + t * 8);
#pragma unroll
            for (int e = 0; e < 8; ++e) o[e] += b2f(vv[e]);
        }
    }
    u16x8 ov;
#pragma unroll
    for (int e = 0; e < 8; ++e) ov[e] = f2b(o[e] * il);
    *(u16x8*)(out + (size_t)s * 2048 + t * 8) = ov;
}

extern "C" void kernel_launch(void* const* d_in, const int* in_sizes, int n_in,
                              void* d_out, int out_size, void* d_ws, size_t ws_size,
                              hipStream_t stream) {
    const int*   positions = (const int*)d_in[0];
    const float* hidden   = (const float*)d_in[1];
    const float* lnw      = (const float*)d_in[2];
    const float* qkvw     = (const float*)d_in[3];
    const float* qnw      = (const float*)d_in[4];
    const float* knw      = (const float*)d_in[5];
    const float* ow       = (const float*)d_in[6];
    float* outp = (float*)d_out;

    char* ws = (char*)d_ws;
    const size_t MB = 1024ull * 1024ull;
    u16* normed = (u16*)(ws + 0 * MB);   // [S][2048] bf16 — dead after QKV gemm
    u16* qraw   = (u16*)(ws + 8 * MB);   // [16][S][128] — dead after attn
    u16* kraw   = (u16*)(ws + 16 * MB);  // [8][S][128]  — dead after attn
    u16* vtr    = (u16*)(ws + 20 * MB);  // [8][128][S]  — dead after attn
    u16* qkvwb  = (u16*)(ws + 24 * MB);  // [4096][2048] bf16 — dead after QKV gemm
    u16* owb    = (u16*)(ws + 0 * MB);   // [2048][2048] bf16, overwrites normed (after qkv)
    u16* attno  = (u16*)(ws + 24 * MB);  // [S][2048] bf16, overwrites qkvwb head
    u16* po     = (u16*)(ws + 32 * MB);  // [3][S][2048] bf16 attn partials (24MB)
    float* pl   = (float*)(ws + 56 * MB);// [3][16][S] f32 attn l-partials

    k_prep    <<<6144, 256, 0, stream>>>(hidden, lnw, normed, qkvw, qkvwb);
    k_gemm_qkv<<<dim3(16, 32), 256, 0, stream>>>(normed, qkvwb, qraw, kraw, vtr, HID);
    k_ropeconv<<<dim3(SEQ, 7), 256, 0, stream>>>(positions, qnw, knw, qraw, kraw, ow, owb);
    k_attn    <<<dim3(63, 16), 256, 0, stream>>>(qraw, kraw, vtr, attno, po, pl);
    k_amerge  <<<1344, 256, 0, stream>>>(po, pl, attno);
    k_gemm_of <<<dim3(16, 32), 256, 0, stream>>>(attno, owb, outp, HID, HID);
}

// Round 15
// 239.002 us; speedup vs baseline: 1.3220x; 1.0233x over previous
//
#include <hip/hip_runtime.h>
#include <hip/hip_bf16.h>
#include <stdint.h>

typedef unsigned short u16;
typedef __attribute__((ext_vector_type(4))) float f32x4;
typedef __attribute__((ext_vector_type(8))) __bf16 bf16x8;
typedef __attribute__((ext_vector_type(8))) unsigned short u16x8;
typedef __attribute__((ext_vector_type(4))) unsigned short u16x4;

#define SEQ 2048
#define HID 2048
#define HD  128

__device__ __forceinline__ float b2f(u16 v) {
    union { float f; unsigned u; } c; c.u = ((unsigned)v) << 16; return c.f;
}
__device__ __forceinline__ u16 f2b(float f) {
    union { float f; unsigned u; } c; c.f = f;
    unsigned r = c.u + 0x7fffu + ((c.u >> 16) & 1u);
    return (u16)(r >> 16);
}
__device__ __forceinline__ bf16x8 tob(u16x8 v) {
    union { u16x8 u; bf16x8 b; } c; c.u = v; return c.b;
}
__device__ __forceinline__ u16x8 ld8(const u16* p) { return *(const u16x8*)p; }

typedef const __attribute__((address_space(1))) unsigned int* gas_ptr;
typedef __attribute__((address_space(3))) unsigned int* las_ptr;
__device__ __forceinline__ void gld16(const void* g, void* l) {
    __builtin_amdgcn_global_load_lds((gas_ptr)g, (las_ptr)l, 16, 0, 0);
}

// ---------------- fused prep: RMSNorm (blocks 0..2047) + qkv-weight conv ----------------
__global__ __launch_bounds__(256) void k_prep(const float* __restrict__ x,
                                              const float* __restrict__ w,
                                              u16* __restrict__ normed,
                                              const float* __restrict__ qkvw,
                                              u16* __restrict__ qkvwb) {
    const int b = blockIdx.x, t = threadIdx.x;
    if (b < 2048) {
        const int row = b;
        const float* xr = x + (size_t)row * HID + t * 8;
        f32x4 xa = *(const f32x4*)xr;
        f32x4 xb = *(const f32x4*)(xr + 4);
        float xf[8]; float ss = 0.f;
#pragma unroll
        for (int e = 0; e < 4; ++e) { xf[e] = xa[e]; xf[e + 4] = xb[e]; }
#pragma unroll
        for (int e = 0; e < 8; ++e) ss += xf[e] * xf[e];
#pragma unroll
        for (int m = 32; m; m >>= 1) ss += __shfl_xor(ss, m);
        __shared__ float red[4];
        if ((t & 63) == 0) red[t >> 6] = ss;
        __syncthreads();
        ss = red[0] + red[1] + red[2] + red[3];
        const float sc = rsqrtf(ss * (1.0f / HID) + 1e-6f);
        f32x4 wa = *(const f32x4*)(w + t * 8);
        f32x4 wb = *(const f32x4*)(w + t * 8 + 4);
        u16x8 ov;
#pragma unroll
        for (int e = 0; e < 4; ++e) {
            ov[e] = f2b(xf[e] * sc * wa[e]);
            ov[e + 4] = f2b(xf[e + 4] * sc * wb[e]);
        }
        *(u16x8*)(normed + (size_t)row * HID + t * 8) = ov;
    } else {
        const size_t i = ((size_t)(b - 2048) * 256 + t) * 8;
        f32x4 a = *(const f32x4*)(qkvw + i);
        f32x4 bb = *(const f32x4*)(qkvw + i + 4);
        u16x8 o;
#pragma unroll
        for (int e = 0; e < 4; ++e) { o[e] = f2b(a[e]); o[e + 4] = f2b(bb[e]); }
        *(u16x8*)(qkvwb + i) = o;
    }
}

// Staging: 8 gld16 per wave per tile. LDS dest linear (rule #21); chunk
// permutation pre-applied to GLOBAL source; reads apply the same XOR.
#define STAGE_G(buf, k0)                                                      \
    do {                                                                      \
        char* a0 = (char*)&As[buf][0][0] + wave * 1024;                       \
        char* a1 = (char*)&As[buf][1][0] + wave * 1024;                       \
        char* b0 = (char*)&Bs[buf][0][0] + wave * 1024;                       \
        char* b1 = (char*)&Bs[buf][1][0] + wave * 1024;                       \
        gld16(ga + (k0), a0);                                                 \
        gld16(ga + (k0) + rowskip, a0 + 4096);                                \
        gld16(ga + (k0) + 32, a1);                                            \
        gld16(ga + (k0) + 32 + rowskip, a1 + 4096);                           \
        gld16(gb + (k0), b0);                                                 \
        gld16(gb + (k0) + rowskip, b0 + 4096);                                \
        gld16(gb + (k0) + 32, b1);                                            \
        gld16(gb + (k0) + 32 + rowskip, b1 + 4096);                           \
    } while (0)

// R5-proven K-loop: dbuf LDS, counted vmcnt(8), swizzled reads. nk = trip count.
#define GEMM_PIPE(nk)                                                         \
    STAGE_G(0, 0);                                                            \
    for (int t = 0; t < (nk); ++t) {                                          \
        const int cur = t & 1;                                                \
        if (t + 1 < (nk)) {                                                   \
            STAGE_G(cur ^ 1, (t + 1) * 64);                                   \
            asm volatile("s_waitcnt vmcnt(8)" ::: "memory");                  \
        } else {                                                              \
            asm volatile("s_waitcnt vmcnt(0)" ::: "memory");                  \
        }                                                                     \
        __builtin_amdgcn_s_barrier();                                         \
        asm volatile("" ::: "memory");                                       \
        _Pragma("unroll")                                                     \
        for (int h = 0; h < 2; ++h) {                                         \
            const u16* as = &As[cur][h][0];                                   \
            const u16* bs = &Bs[cur][h][0];                                   \
            bf16x8 af[4], bfr[4];                                             \
            _Pragma("unroll")                                                 \
            for (int i = 0; i < 4; ++i)                                       \
                af[i] = tob(ld8(as + (wm * 64 + i * 16 + l16) * 32 + ((quad ^ sw) << 3))); \
            _Pragma("unroll")                                                 \
            for (int j = 0; j < 4; ++j)                                       \
                bfr[j] = tob(ld8(bs + (wn * 64 + j * 16 + l16) * 32 + ((quad ^ sw) << 3))); \
            _Pragma("unroll")                                                 \
            for (int i = 0; i < 4; ++i)                                       \
                _Pragma("unroll")                                             \
                for (int j = 0; j < 4; ++j)                                   \
                    acc[i][j] = __builtin_amdgcn_mfma_f32_16x16x32_bf16(af[i], bfr[j], acc[i][j], 0, 0, 0); \
        }                                                                     \
        asm volatile("" ::: "memory");                                       \
        __builtin_amdgcn_s_barrier();                                        \
    }

// ------- QKV GEMM: R5 structure, scatter epilogue -------
__global__ __launch_bounds__(256) void k_gemm_qkv(const u16* __restrict__ A,
                                                  const u16* __restrict__ B,
                                                  u16* __restrict__ qraw,
                                                  u16* __restrict__ kraw,
                                                  u16* __restrict__ vtr,
                                                  int K) {
    __shared__ u16 As[2][2][128 * 32];
    __shared__ u16 Bs[2][2][128 * 32];
    const int tid = threadIdx.x;
    const int wave = tid >> 6, lane = tid & 63, quad = lane >> 4, l16 = lane & 15;
    const int wm = wave >> 1, wn = wave & 1;
    const int sw = (l16 >> 1) & 3;
    const int m0 = blockIdx.x * 128, n0 = blockIdx.y * 128;
    f32x4 acc[4][4];
#pragma unroll
    for (int i = 0; i < 4; ++i)
#pragma unroll
        for (int j = 0; j < 4; ++j) acc[i][j] = (f32x4){0.f, 0.f, 0.f, 0.f};

    const int gchunk = (tid & 3) ^ ((tid >> 3) & 3);
    const u16* ga = A + (size_t)(m0 + (tid >> 2)) * K + gchunk * 8;
    const u16* gb = B + (size_t)(n0 + (tid >> 2)) * K + gchunk * 8;
    const size_t rowskip = (size_t)64 * K;

    GEMM_PIPE(K >> 6)

#pragma unroll
    for (int i = 0; i < 4; ++i) {
        const int row = m0 + wm * 64 + i * 16 + quad * 4;
#pragma unroll
        for (int j = 0; j < 4; ++j) {
            const int col = n0 + wn * 64 + j * 16 + l16;
#pragma unroll
            for (int r = 0; r < 4; ++r) {
                const u16 val = f2b(acc[i][j][r]);
                const int s = row + r;
                if (col < 2048) {
                    const int head = col >> 7, d = col & 127;
                    qraw[((size_t)head * SEQ + s) * HD + d] = val;
                } else if (col < 3072) {
                    const int c = col - 2048, kv = c >> 7, d = c & 127;
                    kraw[((size_t)kv * SEQ + s) * HD + d] = val;
                } else {
                    const int c = col - 3072, kv = c >> 7, d = c & 127;
                    vtr[(size_t)kv * HD * SEQ + (size_t)d * SEQ + s] = val;
                }
            }
        }
    }
}

// ------- O-projection GEMM: BN=64 tiles -> 512 blocks (2/CU overlap, no merge),
//         R5 pipeline with 6 staging loads/thread and counted vmcnt(6), f32 out. -------
__global__ __launch_bounds__(256) void k_gemm_of(const u16* __restrict__ A,
                                                 const u16* __restrict__ B,
                                                 float* __restrict__ C,
                                                 int N, int K) {
    __shared__ u16 As[2][2][128 * 32];
    __shared__ u16 Bs[2][2][64 * 32];
    const int tid = threadIdx.x;
    const int wave = tid >> 6, lane = tid & 63, quad = lane >> 4, l16 = lane & 15;
    const int wm = wave >> 1, wn = wave & 1;
    const int sw = (l16 >> 1) & 3;
    const int m0 = blockIdx.x * 128, n0 = blockIdx.y * 64;
    f32x4 acc[4][2];
#pragma unroll
    for (int i = 0; i < 4; ++i)
#pragma unroll
        for (int j = 0; j < 2; ++j) acc[i][j] = (f32x4){0.f, 0.f, 0.f, 0.f};

    const int gchunk = (tid & 3) ^ ((tid >> 3) & 3);
    const u16* ga = A + (size_t)(m0 + (tid >> 2)) * K + gchunk * 8;
    const u16* gb = B + (size_t)(n0 + (tid >> 2)) * K + gchunk * 8;
    const size_t rowskip = (size_t)64 * K;

#define STAGE_OF(buf, k0)                                                     \
    do {                                                                      \
        char* a0 = (char*)&As[buf][0][0] + wave * 1024;                       \
        char* a1 = (char*)&As[buf][1][0] + wave * 1024;                       \
        char* b0 = (char*)&Bs[buf][0][0] + wave * 1024;                       \
        char* b1 = (char*)&Bs[buf][1][0] + wave * 1024;                       \
        gld16(ga + (k0), a0);                                                 \
        gld16(ga + (k0) + rowskip, a0 + 4096);                                \
        gld16(ga + (k0) + 32, a1);                                            \
        gld16(ga + (k0) + 32 + rowskip, a1 + 4096);                           \
        gld16(gb + (k0), b0);                                                 \
        gld16(gb + (k0) + 32, b1);                                            \
    } while (0)

    STAGE_OF(0, 0);
    const int nk = K >> 6;
    for (int t = 0; t < nk; ++t) {
        const int cur = t & 1;
        if (t + 1 < nk) {
            STAGE_OF(cur ^ 1, (t + 1) * 64);
            asm volatile("s_waitcnt vmcnt(6)" ::: "memory");
        } else {
            asm volatile("s_waitcnt vmcnt(0)" ::: "memory");
        }
        __builtin_amdgcn_s_barrier();
        asm volatile("" ::: "memory");
#pragma unroll
        for (int h = 0; h < 2; ++h) {
            const u16* as = &As[cur][h][0];
            const u16* bs = &Bs[cur][h][0];
            bf16x8 af[4], bfr[2];
#pragma unroll
            for (int i = 0; i < 4; ++i)
                af[i] = tob(ld8(as + (wm * 64 + i * 16 + l16) * 32 + ((quad ^ sw) << 3)));
#pragma unroll
            for (int j = 0; j < 2; ++j)
                bfr[j] = tob(ld8(bs + (wn * 32 + j * 16 + l16) * 32 + ((quad ^ sw) << 3)));
#pragma unroll
            for (int i = 0; i < 4; ++i)
#pragma unroll
                for (int j = 0; j < 2; ++j)
                    acc[i][j] = __builtin_amdgcn_mfma_f32_16x16x32_bf16(af[i], bfr[j], acc[i][j], 0, 0, 0);
        }
        asm volatile("" ::: "memory");
        __builtin_amdgcn_s_barrier();
    }
#undef STAGE_OF

#pragma unroll
    for (int i = 0; i < 4; ++i) {
        const int row = m0 + wm * 64 + i * 16 + quad * 4;
#pragma unroll
        for (int j = 0; j < 2; ++j) {
            const int col = n0 + wn * 32 + j * 16 + l16;
#pragma unroll
            for (int r = 0; r < 4; ++r)
                C[(size_t)(row + r) * N + col] = acc[i][j][r];
        }
    }
}

// ---------------- fused: in-place RoPE + per-head RMSNorm (y<6) + ow conv (y==6) ----------------
__global__ __launch_bounds__(256) void k_ropeconv(const int* __restrict__ pos,
                                                  const float* __restrict__ qw,
                                                  const float* __restrict__ kw,
                                                  u16* __restrict__ qraw,
                                                  u16* __restrict__ kraw,
                                                  const float* __restrict__ ow,
                                                  u16* __restrict__ owb) {
    if (blockIdx.y < 6) {
        const int s = blockIdx.x;
        const int h = blockIdx.y * 4 + (threadIdx.x >> 6);
        const int d = threadIdx.x & 63;
        const bool isq = h < 16;
        u16* row = isq ? (qraw + ((size_t)h * SEQ + s) * HD)
                       : (kraw + ((size_t)(h - 16) * SEQ + s) * HD);
        const float x1 = b2f(row[d]), x2 = b2f(row[d + 64]);
        const float p = (float)pos[s];
        const float inv = exp2f(-(float)d * (2.0f / 128.0f) * 13.287712379549449f);
        const float fr = p * inv;
        const float c = cosf(fr), sn = sinf(fr);
        const float o1 = x1 * c - x2 * sn;
        const float o2 = x2 * c + x1 * sn;
        float ss = o1 * o1 + o2 * o2;
#pragma unroll
        for (int m = 32; m; m >>= 1) ss += __shfl_xor(ss, m);
        const float sc = rsqrtf(ss * (1.0f / HD) + 1e-6f);
        const float* w = isq ? qw : kw;
        row[d] = f2b(o1 * sc * w[d]);
        row[d + 64] = f2b(o2 * sc * w[d + 64]);
    } else {
        const size_t i = ((size_t)blockIdx.x * 256 + threadIdx.x) * 8;
        f32x4 a = *(const f32x4*)(ow + i);
        f32x4 b = *(const f32x4*)(ow + i + 4);
        u16x8 o;
#pragma unroll
        for (int e = 0; e < 4; ++e) { o[e] = f2b(a[e]); o[e + 4] = f2b(b[e]); }
        *(u16x8*)(owb + i) = o;
    }
}

// ---------------- causal flash attention: QBLK=128 + slot-permuted P + split-K ----------------
// Each wave owns TWO 16-row q-slices (u=0,1): 64 MFMA/iter/wave vs 32, with the SAME
// K/V staging, LDS reads (bk/bv reused for both slices), and barrier count -> per-iter
// convoy stall amortized 2x. Q-tiles of 128 rows; split np=1 (Q<=4) / 2 (Q5..9) /
// 3 (Q>=10) keeps max 11 serial iters; 33 blocks/head = 528 blocks, 32KB LDS.
// Slot permutation (R13/R14-proven): K rows staged at rho(kp); QK^T slot (j,quad,r)
// holds P at kpos 32(j>>1)+8*quad+4(j&1)+r == PV A-fragment element -> in-lane pack.
// Partials for rows >= 640 merged by k_amerge.
__global__ __launch_bounds__(256, 2) void k_attn(const u16* __restrict__ qh,
                                                 const u16* __restrict__ kh,
                                                 const u16* __restrict__ vt,
                                                 u16* __restrict__ out,
                                                 u16* __restrict__ po,
                                                 float* __restrict__ pl) {
    const int tid = threadIdx.x;
    const int wave = tid >> 6, lane = tid & 63, quad = lane >> 4, l16 = lane & 15;
    const int head = blockIdx.y;
    const int b = blockIdx.x;            // 0..32
    int Q, part, np;
    if (b < 5)       { Q = b;                    part = 0;            np = 1; }
    else if (b < 15) { Q = 5 + ((b - 5) >> 1);   part = (b - 5) & 1;  np = 2; }
    else             { Q = 10 + (b - 15) / 3;    part = (b - 15) % 3; np = 3; }
    const int kvh = head >> 1;
    const int q0 = Q * 128;
    const int ntiles = 2 * Q + 2;        // causal k-tiles of 64 covering rows q0..q0+127

    __shared__ u16 Ks[64 * 128];
    __shared__ u16 Vts[128 * 64];

    const u16* qbase = qh + ((size_t)head * SEQ + q0 + wave * 32) * HD;
    bf16x8 aq[2][4];
#pragma unroll
    for (int u = 0; u < 2; ++u)
#pragma unroll
        for (int kk = 0; kk < 4; ++kk)
            aq[u][kk] = tob(ld8(qbase + (u * 16 + l16) * HD + kk * 32 + quad * 8));

    f32x4 acco[2][8];
#pragma unroll
    for (int u = 0; u < 2; ++u)
#pragma unroll
        for (int j = 0; j < 8; ++j) acco[u][j] = (f32x4){0.f, 0.f, 0.f, 0.f};
    float lsum[2] = {0.f, 0.f};

    const float sc = 0.08838834764831845f; // 1/sqrt(128)
    const u16* kbase = kh + (size_t)kvh * SEQ * HD;
    const u16* vbase = vt + (size_t)kvh * HD * SEQ;
    const int qrow0 = q0 + wave * 32 + l16; // u=0 row; u=1 adds 16

    const u16* kg0 = kbase + (size_t)tid * 8;
    const u16* vg0 = vbase + (size_t)(tid >> 3) * SEQ + (size_t)(tid & 7) * 8;
    int kst[4], vst[4];
#pragma unroll
    for (int r = 0; r < 4; ++r) {
        const int kp = r * 16 + (tid >> 4);                           // physical tile row
        const int u = (kp & 35) | ((kp & 4) << 2) | ((kp & 24) >> 1); // rho(kp)
        kst[r] = u * 128 + (((tid & 15) ^ (u & 7)) << 3);
        const int vrow = r * 32 + (tid >> 3);
        vst[r] = vrow * 64 + (((tid & 7) ^ (vrow & 7)) << 3);
    }

    // prologue: stage tile kt=part (always < ntiles, ntiles>=2)
    u16x8 kreg[4], vreg[4];
    {
        const size_t koff = (size_t)part * 64;
#pragma unroll
        for (int r = 0; r < 4; ++r) {
            kreg[r] = ld8(kg0 + koff * HD + (size_t)r * 2048);
            vreg[r] = ld8(vg0 + koff + (size_t)r * 32 * SEQ);
        }
#pragma unroll
        for (int r = 0; r < 4; ++r) {
            *(u16x8*)(&Ks[0] + kst[r]) = kreg[r];
            *(u16x8*)(&Vts[0] + vst[r]) = vreg[r];
        }
    }
    __syncthreads();

    for (int kt = part; kt < ntiles; kt += np) {
        const bool havenext = (kt + np) < ntiles;
        if (havenext) {
            const size_t koff = (size_t)(kt + np) * 64;
#pragma unroll
            for (int r = 0; r < 4; ++r) {
                kreg[r] = ld8(kg0 + koff * HD + (size_t)r * 2048);
                vreg[r] = ld8(vg0 + koff + (size_t)r * 32 * SEQ);
            }
        }

        // S^T = K Q^T for both 16-row slices (bk loaded once, used twice)
        f32x4 accs[2][4];
#pragma unroll
        for (int u = 0; u < 2; ++u)
#pragma unroll
            for (int j = 0; j < 4; ++j) accs[u][j] = (f32x4){0.f, 0.f, 0.f, 0.f};
#pragma unroll
        for (int kk = 0; kk < 4; ++kk) {
#pragma unroll
            for (int j = 0; j < 4; ++j) {
                const int krow = j * 16 + l16;
                const bf16x8 bk = tob(ld8(&Ks[0] + krow * 128 + (((kk * 4 + quad) ^ (krow & 7)) << 3)));
                accs[0][j] = __builtin_amdgcn_mfma_f32_16x16x32_bf16(bk, aq[0][kk], accs[0][j], 0, 0, 0);
                accs[1][j] = __builtin_amdgcn_mfma_f32_16x16x32_bf16(bk, aq[1][kk], accs[1][j], 0, 0, 0);
            }
        }

        // P = exp(s*sc) (M=0), causal mask; pack PV A-fragments IN-LANE per slice
        const int k0 = kt * 64;
        u16x8 apk[2][2];
#pragma unroll
        for (int u = 0; u < 2; ++u) {
            const int qrg = qrow0 + u * 16;
#pragma unroll
            for (int j = 0; j < 4; ++j) {
#pragma unroll
                for (int r = 0; r < 4; ++r) {
                    const int kpos = k0 + ((j >> 1) << 5) + (quad << 3) + ((j & 1) << 2) + r;
                    const float pv = (kpos > qrg) ? 0.f : __expf(accs[u][j][r] * sc);
                    lsum[u] += pv;
                    apk[u][j >> 1][((j & 1) << 2) + r] = f2b(pv);
                }
            }
        }

        // O += P V (ap lane-local; bv loaded once, used twice)
#pragma unroll
        for (int kk = 0; kk < 2; ++kk) {
            const bf16x8 ap0 = tob(apk[0][kk]);
            const bf16x8 ap1 = tob(apk[1][kk]);
#pragma unroll
            for (int j = 0; j < 8; ++j) {
                const int vrow = j * 16 + l16;
                const bf16x8 bv = tob(ld8(&Vts[0] + vrow * 64 + (((kk * 4 + quad) ^ (vrow & 7)) << 3)));
                acco[0][j] = __builtin_amdgcn_mfma_f32_16x16x32_bf16(ap0, bv, acco[0][j], 0, 0, 0);
                acco[1][j] = __builtin_amdgcn_mfma_f32_16x16x32_bf16(ap1, bv, acco[1][j], 0, 0, 0);
            }
        }

        __syncthreads(); // all reads of this tile done
        if (havenext) {
#pragma unroll
            for (int r = 0; r < 4; ++r) {
                *(u16x8*)(&Ks[0] + kst[r]) = kreg[r];
                *(u16x8*)(&Vts[0] + vst[r]) = vreg[r];
            }
        }
        __syncthreads(); // stores visible before next-iter reads
    }

    // per-slice l reduction + output
#pragma unroll
    for (int u = 0; u < 2; ++u) {
        float v = lsum[u];
        v += __shfl_xor(v, 16);
        v += __shfl_xor(v, 32);
        const int rowb = q0 + wave * 32 + u * 16 + quad * 4;

        if (np == 1) {
            f32x4 il;
#pragma unroll
            for (int r = 0; r < 4; ++r) il[r] = 1.0f / __shfl(v, quad * 4 + r);
#pragma unroll
            for (int j = 0; j < 8; ++j) {
                const int col = head * HD + j * 16 + l16;
#pragma unroll
                for (int r = 0; r < 4; ++r)
                    out[(size_t)(rowb + r) * 2048 + col] = f2b(acco[u][j][r] * il[r]);
            }
        } else {
            u16* pob = po + (size_t)part * SEQ * 2048;
            float* plb = pl + (size_t)part * 16 * SEQ;
            if (lane < 16) plb[head * SEQ + q0 + wave * 32 + u * 16 + l16] = v;
#pragma unroll
            for (int j = 0; j < 8; ++j) {
                const int col = head * HD + j * 16 + l16;
#pragma unroll
                for (int r = 0; r < 4; ++r)
                    pob[(size_t)(rowb + r) * 2048 + col] = f2b(acco[u][j][r]);
            }
        }
    }
}

// ---------------- split-K merge + normalize for rows s >= 640 ----------------
__global__ __launch_bounds__(256) void k_amerge(const u16* __restrict__ po,
                                                const float* __restrict__ pl,
                                                u16* __restrict__ out) {
    const int s = blockIdx.x + 640;
    const int Q = s >> 7;
    const int np = (Q >= 10) ? 3 : 2;
    const int t = threadIdx.x;
    const int head = t >> 4;

    float l = 0.f;
#pragma unroll
    for (int p = 0; p < 3; ++p)
        if (p < np) l += pl[(size_t)p * 16 * SEQ + head * SEQ + s];
    const float il = 1.0f / l;

    float o[8] = {0.f, 0.f, 0.f, 0.f, 0.f, 0.f, 0.f, 0.f};
#pragma unroll
    for (int p = 0; p < 3; ++p) {
        if (p < np) {
            const u16x8 vv = ld8(po + (size_t)p * SEQ * 2048 + (size_t)s * 2048 + t * 8);
#pragma unroll
            for (int e = 0; e < 8; ++e) o[e] += b2f(vv[e]);
        }
    }
    u16x8 ov;
#pragma unroll
    for (int e = 0; e < 8; ++e) ov[e] = f2b(o[e] * il);
    *(u16x8*)(out + (size_t)s * 2048 + t * 8) = ov;
}

extern "C" void kernel_launch(void* const* d_in, const int* in_sizes, int n_in,
                              void* d_out, int out_size, void* d_ws, size_t ws_size,
                              hipStream_t stream) {
    const int*   positions = (const int*)d_in[0];
    const float* hidden   = (const float*)d_in[1];
    const float* lnw      = (const float*)d_in[2];
    const float* qkvw     = (const float*)d_in[3];
    const float* qnw      = (const float*)d_in[4];
    const float* knw      = (const float*)d_in[5];
    const float* ow       = (const float*)d_in[6];
    float* outp = (float*)d_out;

    char* ws = (char*)d_ws;
    const size_t MB = 1024ull * 1024ull;
    u16* normed = (u16*)(ws + 0 * MB);   // [S][2048] bf16 — dead after QKV gemm
    u16* qraw   = (u16*)(ws + 8 * MB);   // [16][S][128] — dead after attn
    u16* kraw   = (u16*)(ws + 16 * MB);  // [8][S][128]  — dead after attn
    u16* vtr    = (u16*)(ws + 20 * MB);  // [8][128][S]  — dead after attn
    u16* qkvwb  = (u16*)(ws + 24 * MB);  // [4096][2048] bf16 — dead after QKV gemm
    u16* owb    = (u16*)(ws + 0 * MB);   // [2048][2048] bf16, overwrites normed (after qkv)
    u16* attno  = (u16*)(ws + 24 * MB);  // [S][2048] bf16, overwrites qkvwb head
    u16* po     = (u16*)(ws + 32 * MB);  // [3][S][2048] bf16 attn partials (24MB)
    float* pl   = (float*)(ws + 56 * MB);// [3][16][S] f32 attn l-partials

    k_prep    <<<6144, 256, 0, stream>>>(hidden, lnw, normed, qkvw, qkvwb);
    k_gemm_qkv<<<dim3(16, 32), 256, 0, stream>>>(normed, qkvwb, qraw, kraw, vtr, HID);
    k_ropeconv<<<dim3(SEQ, 7), 256, 0, stream>>>(positions, qnw, knw, qraw, kraw, ow, owb);
    k_attn    <<<dim3(33, 16), 256, 0, stream>>>(qraw, kraw, vtr, attno, po, pl);
    k_amerge  <<<1408, 256, 0, stream>>>(po, pl, attno);
    k_gemm_of <<<dim3(16, 32), 256, 0, stream>>>(attno, owb, outp, HID, HID);
}